// Round 9
// baseline (335.485 us; speedup 1.0000x reference)
//
#include <hip/hip_runtime.h>
#include <hip/hip_bf16.h>

// x: [B=1024, N=65536] f32, index: [N] i32 permutation, group size 64.
#define BATCH   1024
#define NEUR    65536
#define NGRP    1024                  // groups (thread t owns group t)
#define BLK     1024
#define NCHUNK  4
#define CHUNK   (NEUR / NCHUNK)       // 16384 floats per chunk (64 KB LDS)
#define CHUNK_F4 (CHUNK / 4)
#define F4T     (CHUNK_F4 / BLK)      // 4 float4 per thread
#define KMAX    24                    // padded slots per (chunk, group) cell
#define SENT    CHUNK                 // sentinel LDS slot holding 0.0f
#define ROW_F4  (NEUR / 4)
#define C_ITERS (ROW_F4 / BLK)        // 16
#define BUCKET_ELEMS (NCHUNK * KMAX * NGRP)   // 98304 u16
#define SPILL_CAP 1024
#define NSUM    (BATCH * NGRP)        // 4 MB

typedef float f32x4 __attribute__((ext_vector_type(4)));   // native vector for
                                                           // nontemporal builtin

// ws: [group_of 256 KB][bucket 192 KB][spill 4 KB][sums 4 MB][cnt 4 KB]

__global__ void init_tables(unsigned short* __restrict__ bucket,
                            unsigned int* __restrict__ spill,
                            float* __restrict__ sums,
                            unsigned int* __restrict__ cnt) {
    int i = blockIdx.x * blockDim.x + threadIdx.x;
    if (i < BUCKET_ELEMS) bucket[i] = (unsigned short)SENT;
    if (i == 0) spill[0] = 0;
    if (i < NSUM) sums[i] = 0.0f;
    if (i < BATCH) cnt[i] = 0;         // must re-zero every call (graph replay)
}

// Wave == one group. Ballot/popcount slots each member into its source-chunk
// cell; overflow -> spill list (~40 entries). Builds inverse-perm table too.
__global__ void build_tables(const int* __restrict__ index,
                             int* __restrict__ group_of,
                             unsigned short* __restrict__ bucket,
                             unsigned int* __restrict__ spill) {
    const int p    = blockIdx.x * blockDim.x + threadIdx.x;
    const int lane = threadIdx.x & 63;
    const int g    = p >> 6;
    const int s    = index[p];
    group_of[s] = g;
    const int c = s / CHUNK;
    unsigned long long mc = 0;
    #pragma unroll
    for (int cc = 0; cc < NCHUNK; ++cc) {
        unsigned long long m = __ballot(c == cc);
        if (cc == c) mc = m;
    }
    const int k = __popcll(mc & ((1ull << lane) - 1ull));
    if (k < KMAX) {
        bucket[((size_t)c * KMAX + k) * NGRP + g] = (unsigned short)(s & (CHUNK - 1));
    } else {
        unsigned int pos = atomicAdd(spill, 1u);
        if (pos < SPILL_CAP - 1)
            spill[1 + pos] = ((unsigned)g << 16) | (unsigned)s;
    }
}

// One block per (row, chunk); the LAST arriver of a row finalizes it (split-K
// tail election) — the row re-read happens microseconds after staging, so it
// is served by the same XCD's L2 (XCD swizzle pins all 4 chunks of a row to
// one XCD). Nontemporal out-stores keep the 256 MB output stream from
// evicting x. No separate k3 launch, no cold re-read (R7's ~130 us tail).
__global__ __launch_bounds__(BLK, 8)
void k_main(const float* __restrict__ x,
            const int* __restrict__ group_of,
            const unsigned short* __restrict__ bucket,
            const unsigned int* __restrict__ spill,
            float* __restrict__ sums,
            unsigned int* __restrict__ cnt,
            float* __restrict__ out) {
    __shared__ float xs[CHUNK + 32];   // chunk + sentinel; reused as rsum in tail
    __shared__ unsigned int lastflag;

    // XCD-chunked swizzle: hw maps raw%8 -> XCD; give XCD k rows [128k,128k+128)
    const int raw = blockIdx.x;                        // 0..4095
    const int w   = (raw & 7) * (int)(gridDim.x >> 3) + (raw >> 3);
    const int b   = w >> 2;
    const int c   = w & 3;
    const int t   = threadIdx.x;

    if (t == 0) xs[SENT] = 0.0f;

    const float* __restrict__ xrow = x + (size_t)b * NEUR;
    const float4* __restrict__ src = (const float4*)(xrow + (size_t)c * CHUNK);
    #pragma unroll
    for (int i = 0; i < F4T; ++i) ((float4*)xs)[i * BLK + t] = src[i * BLK + t];
    __syncthreads();

    // 24 branch-free gather-adds (pads hit the 0.0 sentinel) — R6/R7-proven.
    const unsigned short* __restrict__ bk = bucket + (size_t)c * KMAX * NGRP + t;
    float a0 = 0.0f, a1 = 0.0f;
    #pragma unroll
    for (int k = 0; k < KMAX; k += 2) {
        a0 += xs[bk[k * NGRP]];
        a1 += xs[bk[(k + 1) * NGRP]];
    }
    unsafeAtomicAdd(&sums[b * NGRP + t], a0 + a1);

    __syncthreads();                   // all waves' atomics issued before election
    if (t == 0) {
        unsigned int old = __hip_atomic_fetch_add(&cnt[b], 1u, __ATOMIC_ACQ_REL,
                                                  __HIP_MEMORY_SCOPE_AGENT);
        lastflag = (old == NCHUNK - 1u);
    }
    __syncthreads();
    if (!lastflag) return;

    // ---- tail: this block finalizes row b ----
    float s = __hip_atomic_load(&sums[b * NGRP + t], __ATOMIC_RELAXED,
                                __HIP_MEMORY_SCOPE_AGENT);
    const unsigned int ns = spill[0];  // ~40 entries: broadcast scan
    for (unsigned int e = 0; e < ns; ++e) {
        const unsigned int ent = spill[1 + e];
        if ((int)(ent >> 16) == t) s += xrow[ent & 0xFFFFu];
    }
    float* rsum = xs;                  // reuse LDS (post-barrier)
    rsum[t] = 1.0f / s;
    __syncthreads();

    const float4* __restrict__ xrow4 = (const float4*)xrow;
    const int4*   __restrict__ gof4  = (const int4*)group_of;
    f32x4*        __restrict__ orow4 = (f32x4*)(out + (size_t)b * NEUR);

    #pragma unroll
    for (int it = 0; it < C_ITERS; ++it) {
        const int e = it * BLK + t;
        const float4 v = xrow4[e];     // L2-hot: staged microseconds ago, same XCD
        const int4  g = gof4[e];       // 256 KB table, L2-resident
        f32x4 o;
        o.x = v.x * rsum[g.x];
        o.y = v.y * rsum[g.y];
        o.z = v.z * rsum[g.z];
        o.w = v.w * rsum[g.w];
        __builtin_nontemporal_store(o, &orow4[e]);  // don't evict x
    }
}

extern "C" void kernel_launch(void* const* d_in, const int* in_sizes, int n_in,
                              void* d_out, int out_size, void* d_ws, size_t ws_size,
                              hipStream_t stream) {
    const float* x     = (const float*)d_in[0];
    const int*   index = (const int*)d_in[1];
    float*       out   = (float*)d_out;

    int*            group_of = (int*)d_ws;                          // 256 KB
    unsigned short* bucket   = (unsigned short*)(group_of + NEUR);  // 192 KB
    unsigned int*   spill    = (unsigned int*)(bucket + BUCKET_ELEMS); // 4 KB
    float*          sums     = (float*)(spill + SPILL_CAP);         // 4 MB
    unsigned int*   cnt      = (unsigned int*)(sums + NSUM);        // 4 KB

    init_tables<<<NSUM / BLK, BLK, 0, stream>>>(bucket, spill, sums, cnt);
    build_tables<<<NEUR / BLK, BLK, 0, stream>>>(index, group_of, bucket, spill);
    k_main<<<BATCH * NCHUNK, BLK, 0, stream>>>(x, group_of, bucket, spill,
                                               sums, cnt, out);
}

// Round 10
// 158.071 us; speedup vs baseline: 2.1224x; 2.1224x over previous
//
#include <hip/hip_runtime.h>
#include <hip/hip_bf16.h>

// x: [B=1024, N=65536] f32, index: [N] i32 permutation, group size 64.
#define BATCH   1024
#define NEUR    65536
#define NGRP    1024                  // groups (thread t owns group t)
#define BLK     1024
#define NCHUNK  4
#define CHUNK   (NEUR / NCHUNK)       // 16384 floats per chunk (64 KB LDS)
#define CHUNK_F4 (CHUNK / 4)
#define F4T     (CHUNK_F4 / BLK)      // 4 float4 per thread
#define KMAX    24                    // padded slots per (chunk, group) cell
#define SENT    CHUNK                 // sentinel LDS slot holding 0.0f
#define ROW_F4  (NEUR / 4)            // 16384
#define HALF_F4 (ROW_F4 / 2)          // 8192
#define H_ITERS (HALF_F4 / BLK)       // 8
#define BUCKET_ELEMS (NCHUNK * NGRP * KMAX)   // 98304 u16 (transposed layout)
#define SPILL_CAP 1024
#define NSUM    (BATCH * NGRP)        // 1M floats

typedef float          f32x4  __attribute__((ext_vector_type(4)));
typedef unsigned short u16x8  __attribute__((ext_vector_type(8)));

// ws: [group_of 256 KB][bucket 192 KB][part 16 MB][spill 4 KB]

__global__ void init_tables(unsigned short* __restrict__ bucket,
                            unsigned int* __restrict__ spill) {
    int i = blockIdx.x * blockDim.x + threadIdx.x;
    if (i < BUCKET_ELEMS) bucket[i] = (unsigned short)SENT;
    if (i == 0) spill[0] = 0;
}

// Wave == one group. Ballot/popcount slots each member into its source-chunk
// cell. Bucket is TRANSPOSED: bucket[(c*NGRP+g)*KMAX + k] so k1 reads each
// thread's 24 slots as 3 contiguous ushort8 (R10: was 24 strided u16 loads).
__global__ void build_tables(const int* __restrict__ index,
                             int* __restrict__ group_of,
                             unsigned short* __restrict__ bucket,
                             unsigned int* __restrict__ spill) {
    const int p    = blockIdx.x * blockDim.x + threadIdx.x;
    const int lane = threadIdx.x & 63;
    const int g    = p >> 6;
    const int s    = index[p];
    group_of[s] = g;
    const int c = s / CHUNK;
    unsigned long long mc = 0;
    #pragma unroll
    for (int cc = 0; cc < NCHUNK; ++cc) {
        unsigned long long m = __ballot(c == cc);
        if (cc == c) mc = m;
    }
    const int k = __popcll(mc & ((1ull << lane) - 1ull));
    if (k < KMAX) {
        bucket[((size_t)(c * NGRP + g)) * KMAX + k] = (unsigned short)(s & (CHUNK - 1));
    } else {
        unsigned int pos = atomicAdd(spill, 1u);
        if (pos < SPILL_CAP - 1)
            spill[1 + pos] = ((unsigned)g << 16) | (unsigned)s;
    }
}

// k1: one block per (row, chunk) — 4096 independent blocks. Stage 64 KB chunk,
// one barrier, 24 branch-free sentinel-padded gather-adds (3x ushort8 slot
// loads), then ONE PLAIN STORE of the partial (no atomics, no init'd sums).
__global__ __launch_bounds__(BLK, 8)
void k1_partial(const float* __restrict__ x,
                const unsigned short* __restrict__ bucket,
                float* __restrict__ part) {
    __shared__ float xs[CHUNK + 16];
    const int bc = blockIdx.x;
    const int b  = bc >> 2;            // row
    const int c  = bc & 3;             // chunk
    const int t  = threadIdx.x;

    if (t == 0) xs[SENT] = 0.0f;

    const float4* __restrict__ src =
        (const float4*)(x + (size_t)b * NEUR + (size_t)c * CHUNK);
    #pragma unroll
    for (int i = 0; i < F4T; ++i) ((float4*)xs)[i * BLK + t] = src[i * BLK + t];
    __syncthreads();

    const unsigned short* __restrict__ bk =
        bucket + ((size_t)(c * NGRP + t)) * KMAX;          // 48 B contiguous
    const u16x8 w0 = *(const u16x8*)(bk);
    const u16x8 w1 = *(const u16x8*)(bk + 8);
    const u16x8 w2 = *(const u16x8*)(bk + 16);

    float a0 = 0.0f, a1 = 0.0f;
    #pragma unroll
    for (int j = 0; j < 8; ++j) {
        a0 += xs[w0[j]];
        a1 += xs[w1[j]];
        a0 += xs[w2[j]];               // pads hit the 0.0 sentinel
    }
    part[(size_t)c * NSUM + b * NGRP + t] = a0 + a1;       // coalesced 4 KB
}

// k3: one block per HALF-row (2048 blocks — 2x R7's granularity), reverse
// order so the L3-hottest rows go first. Sum the 4 partials coalesced, spill
// fixup, reciprocal, then the proven coalesced scale + nontemporal store.
__global__ __launch_bounds__(BLK, 8)
void k3_scale(const float* __restrict__ x,
              const int* __restrict__ group_of,
              const float* __restrict__ part,
              const unsigned int* __restrict__ spill,
              float* __restrict__ out) {
    __shared__ float rsum[NGRP];       // 4 KB only
    const int rb   = blockIdx.x;
    const int b    = (BATCH - 1) - (rb >> 1);
    const int half = rb & 1;
    const int t    = threadIdx.x;
    const float* __restrict__ xrow = x + (size_t)b * NEUR;

    float s = part[0 * NSUM + b * NGRP + t]
            + part[1 * NSUM + b * NGRP + t]
            + part[2 * NSUM + b * NGRP + t]
            + part[3 * NSUM + b * NGRP + t];
    const unsigned int ns = spill[0];  // ~40 entries: broadcast scan
    for (unsigned int e = 0; e < ns; ++e) {
        const unsigned int ent = spill[1 + e];
        if ((int)(ent >> 16) == t) s += xrow[ent & 0xFFFFu];
    }
    rsum[t] = 1.0f / s;
    __syncthreads();

    const float4* __restrict__ xrow4 = (const float4*)xrow;
    const int4*   __restrict__ gof4  = (const int4*)group_of;
    f32x4*        __restrict__ orow4 = (f32x4*)(out + (size_t)b * NEUR);

    #pragma unroll
    for (int it = 0; it < H_ITERS; ++it) {
        const int e = half * HALF_F4 + it * BLK + t;
        const float4 v = xrow4[e];     // L3-hot re-read (FETCH stays ~x-once)
        const int4  g = gof4[e];       // 256 KB table, L2-resident
        f32x4 o;
        o.x = v.x * rsum[g.x];
        o.y = v.y * rsum[g.y];
        o.z = v.z * rsum[g.z];
        o.w = v.w * rsum[g.w];
        __builtin_nontemporal_store(o, &orow4[e]);  // don't evict x from L3
    }
}

extern "C" void kernel_launch(void* const* d_in, const int* in_sizes, int n_in,
                              void* d_out, int out_size, void* d_ws, size_t ws_size,
                              hipStream_t stream) {
    const float* x     = (const float*)d_in[0];
    const int*   index = (const int*)d_in[1];
    float*       out   = (float*)d_out;

    int*            group_of = (int*)d_ws;                          // 256 KB
    unsigned short* bucket   = (unsigned short*)(group_of + NEUR);  // 192 KB
    float*          part     = (float*)(bucket + BUCKET_ELEMS);     // 16 MB
    unsigned int*   spill    = (unsigned int*)(part + NCHUNK * NSUM); // 4 KB

    init_tables<<<BUCKET_ELEMS / BLK, BLK, 0, stream>>>(bucket, spill);
    build_tables<<<NEUR / BLK, BLK, 0, stream>>>(index, group_of, bucket, spill);
    k1_partial<<<BATCH * NCHUNK, BLK, 0, stream>>>(x, bucket, part);
    k3_scale<<<BATCH * 2, BLK, 0, stream>>>(x, group_of, part, spill, out);
}